// Round 1
// baseline (561.366 us; speedup 1.0000x reference)
//
#include <hip/hip_runtime.h>

#define B_  8
#define C_  32
#define O_  32
#define H_  252
#define W_  252
#define TS  16
#define TLW 21   // LDS tile stride (20 + 1 pad)

__global__ __launch_bounds__(256) void fftconv_direct(
    const float* __restrict__ x,      // [8][32][252][252]
    const float* __restrict__ w,      // [32][32][5][5]
    float* __restrict__ out)          // [8][32][252][252]
{
    __shared__ float tile[20 * TLW];
    __shared__ int rowmap[20];
    __shared__ int colmap[20];

    const int tid  = threadIdx.x;
    const int bidx = blockIdx.x;       // b*256 + tile index
    const int b    = bidx >> 8;
    const int t2   = bidx & 255;
    const int i0   = (t2 >> 4) * TS;
    const int j0   = (t2 & 15) * TS;

    // Precompute padded->source index maps (reflect pad + circular wrap).
    if (tid < 40) {
        int k    = (tid < 20) ? tid : tid - 20;
        int base = (tid < 20) ? i0  : j0;
        int r = (base + 1 + k) & 255;   // padded coordinate, mod 256 (circular)
        int t = r - 2;                  // unpadded coordinate
        int m = (t < 0) ? -t : ((t > 251) ? 502 - t : t);  // reflect
        if (tid < 20) rowmap[k] = m; else colmap[k] = m;
    }
    __syncthreads();

    const int li = tid >> 4;
    const int lj = tid & 15;

    float acc[32];
    #pragma unroll
    for (int o = 0; o < 32; ++o) acc[o] = 0.0f;

    for (int ci = 0; ci < 32; ++ci) {
        const float* xc = x + ((size_t)(b * 32 + ci)) * (H_ * W_);

        // stage 20x20 patch
        {
            int idx = tid;
            if (idx < 400)
                tile[(idx / 20) * TLW + (idx % 20)] =
                    xc[(size_t)rowmap[idx / 20] * W_ + colmap[idx % 20]];
            idx = tid + 256;
            if (idx < 400)
                tile[(idx / 20) * TLW + (idx % 20)] =
                    xc[(size_t)rowmap[idx / 20] * W_ + colmap[idx % 20]];
        }
        __syncthreads();

        // 25 tap values into registers
        float v[25];
        #pragma unroll
        for (int da = 0; da < 5; ++da)
            #pragma unroll
            for (int db = 0; db < 5; ++db)
                v[da * 5 + db] = tile[(li + da) * TLW + (lj + db)];

        // 32 output channels x 25 taps; weight index is wave-uniform -> s_load
        const float* wc = w + ci * 25;
        #pragma unroll
        for (int o = 0; o < 32; ++o) {
            const float* wo = wc + (size_t)o * (32 * 25);
            #pragma unroll
            for (int da = 0; da < 5; ++da)
                #pragma unroll
                for (int db = 0; db < 5; ++db)
                    acc[o] = fmaf(v[da * 5 + db],
                                  wo[(4 - da) * 5 + (4 - db)], acc[o]);
        }
        __syncthreads();   // all tap reads done before next staging
    }

    const int i = i0 + li;
    const int j = j0 + lj;
    if (i < H_ && j < W_) {
        size_t o0 = ((size_t)(b * 32)) * (H_ * W_) + (size_t)i * W_ + j;
        #pragma unroll
        for (int o = 0; o < 32; ++o)
            out[o0 + (size_t)o * (H_ * W_)] = acc[o];
    }
}

extern "C" void kernel_launch(void* const* d_in, const int* in_sizes, int n_in,
                              void* d_out, int out_size, void* d_ws, size_t ws_size,
                              hipStream_t stream) {
    const float* x = (const float*)d_in[0];
    const float* w = (const float*)d_in[1];
    float* out = (float*)d_out;

    dim3 grid(B_ * 256);   // 8 batches x (16x16 tiles)
    dim3 block(256);
    hipLaunchKernelGGL(fftconv_direct, grid, block, 0, stream, x, w, out);
}

// Round 2
// 88.980 us; speedup vs baseline: 6.3089x; 6.3089x over previous
//
#include <hip/hip_runtime.h>

typedef __attribute__((ext_vector_type(8))) short bf16x8;
typedef __attribute__((ext_vector_type(4))) float f32x4;

#define HW_   252
#define PLANE 63504   // 252*252
#define NCH   32

__device__ __forceinline__ unsigned short f2bf(float f) {
    unsigned u = __builtin_bit_cast(unsigned, f);
    u += 0x7FFFu + ((u >> 16) & 1u);      // round-to-nearest-even
    return (unsigned short)(u >> 16);
}

// Pack weights: wp[t][o][ci] = bf16(w[o][ci][4-da][4-db]), t = da*5+db (flip folded in)
__global__ void pack_w_kernel(const float* __restrict__ w, unsigned short* __restrict__ wp) {
    int e = blockIdx.x * 256 + threadIdx.x;   // [25][32][32] = 25600
    if (e >= 25600) return;
    int ci = e & 31;
    int o  = (e >> 5) & 31;
    int t  = e >> 10;
    int da = t / 5, db = t - da * 5;
    wp[e] = f2bf(w[((o * 32 + ci) * 5 + (4 - da)) * 5 + (4 - db)]);
}

// D[16o x 16pix] += A[16o x 32ci] * B[32ci x 16pix] per tap; 25 taps = K 800.
// A frag: lane holds A[o=lane&15][ci=8*(lane>>4)+j]  -> 16B from wp[t][o][ci_base]
// B frag: lane holds B[ci=8*(lane>>4)+j][pix=lane&15] -> 16B from xl[row][col][ci_base] (swizzled)
// D frag: D[o=4*(lane>>4)+q][pix=lane&15]  (m89-verified layout)
template<bool WLDS>
__global__ __launch_bounds__(256) void conv_mfma(
    const float* __restrict__ x,
    const float* __restrict__ w_raw,
    const unsigned short* __restrict__ wp,
    float* __restrict__ out)
{
    __shared__ unsigned short xl[12800];            // [20][20][32] bf16, 16B-unit XOR swizzle
    __shared__ unsigned short wl[WLDS ? 25600 : 16];
    __shared__ int rmap[20], cmap[20];

    const int tid = threadIdx.x;
    const int bid = blockIdx.x;
    const int b  = bid >> 8;
    const int rt = (bid >> 4) & 15;
    const int ct = bid & 15;
    const int i0 = rt * 16, j0 = ct * 16;

    // reflect+circular index maps for the 20 padded rows/cols this tile touches
    if (tid < 40) {
        int k    = tid < 20 ? tid : tid - 20;
        int base = tid < 20 ? i0  : j0;
        int r = (base + 1 + k) & 255;
        int t = r - 2;
        int m = t < 0 ? -t : (t > 251 ? 502 - t : t);
        if (tid < 20) rmap[k] = m; else cmap[k] = m;
    }

    if (WLDS) {
        for (int e = tid; e < 25600; e += 256) {
            int o   = e / 800;
            int rem = e - o * 800;
            int ci  = rem / 25;
            int kd  = rem - ci * 25;
            wl[(24 - kd) * 1024 + o * 32 + ci] = f2bf(w_raw[e]);
        }
    }
    __syncthreads();

    // Stage 20x20x32 patch: task=(row,g,col); 8 coalesced dword reads -> 1 ds_write_b128
    for (int task = tid; task < 1600; task += 256) {
        int col = task % 20;
        int g   = (task / 20) & 3;
        int row = task / 80;
        const float* src = x + (size_t)(b * NCH + g * 8) * PLANE
                             + (size_t)rmap[row] * HW_ + cmap[col];
        unsigned short pk[8];
        #pragma unroll
        for (int q = 0; q < 8; ++q) pk[q] = f2bf(src[q * PLANE]);
        int off = ((row * 20 + col) << 6) + ((g ^ (col & 3)) << 4);
        *reinterpret_cast<uint4*>(reinterpret_cast<char*>(xl) + off)
            = *reinterpret_cast<const uint4*>(pk);
    }
    __syncthreads();

    const int lane  = tid & 63;
    const int wid   = tid >> 6;
    const int lm    = lane & 15;   // o-within-16 (A) / pixel col (B,D)
    const int lg    = lane >> 4;   // k-group
    const int rbase = wid * 4;     // wave's 4 output rows

    f32x4 acc[4][2];
    #pragma unroll
    for (int rr = 0; rr < 4; ++rr) {
        acc[rr][0] = (f32x4){0.f, 0.f, 0.f, 0.f};
        acc[rr][1] = (f32x4){0.f, 0.f, 0.f, 0.f};
    }

    const char* wbase = WLDS ? (const char*)wl : (const char*)wp;
    const int afix = (lm << 6) + (lg << 4);
    const char* xlb = reinterpret_cast<const char*>(xl);

    #pragma unroll
    for (int da = 0; da < 5; ++da) {
        #pragma unroll
        for (int db = 0; db < 5; ++db) {
            const int t = da * 5 + db;
            bf16x8 a0 = *reinterpret_cast<const bf16x8*>(wbase + (t << 11) + afix);
            bf16x8 a1 = *reinterpret_cast<const bf16x8*>(wbase + (t << 11) + 1024 + afix);
            const int col  = lm + db;
            const int coff = (col << 6) + ((lg ^ (col & 3)) << 4);
            #pragma unroll
            for (int rr = 0; rr < 4; ++rr) {
                const int row = rbase + rr + da;
                bf16x8 bf = *reinterpret_cast<const bf16x8*>(xlb + ((row * 20) << 6) + coff);
                acc[rr][0] = __builtin_amdgcn_mfma_f32_16x16x32_bf16(a0, bf, acc[rr][0], 0, 0, 0);
                acc[rr][1] = __builtin_amdgcn_mfma_f32_16x16x32_bf16(a1, bf, acc[rr][1], 0, 0, 0);
            }
        }
    }

    // writeback: o = mt*16 + lg*4 + q, pixel col = lm
    const int j = j0 + lm;
    #pragma unroll
    for (int rr = 0; rr < 4; ++rr) {
        const int i = i0 + rbase + rr;
        if (i < HW_ && j < HW_) {
            size_t rowoff = (size_t)(b * NCH) * PLANE + (size_t)i * HW_ + j;
            #pragma unroll
            for (int mt = 0; mt < 2; ++mt)
                #pragma unroll
                for (int q = 0; q < 4; ++q) {
                    int o = mt * 16 + lg * 4 + q;
                    out[rowoff + (size_t)o * PLANE] = acc[rr][mt][q];
                }
        }
    }
}

extern "C" void kernel_launch(void* const* d_in, const int* in_sizes, int n_in,
                              void* d_out, int out_size, void* d_ws, size_t ws_size,
                              hipStream_t stream) {
    const float* x = (const float*)d_in[0];
    const float* w = (const float*)d_in[1];
    float* out = (float*)d_out;

    if (ws_size >= 25600u * sizeof(unsigned short)) {
        unsigned short* wp = (unsigned short*)d_ws;
        hipLaunchKernelGGL(pack_w_kernel, dim3(100), dim3(256), 0, stream, w, wp);
        hipLaunchKernelGGL((conv_mfma<false>), dim3(2048), dim3(256), 0, stream,
                           x, w, (const unsigned short*)wp, out);
    } else {
        hipLaunchKernelGGL((conv_mfma<true>), dim3(2048), dim3(256), 0, stream,
                           x, w, (const unsigned short*)nullptr, out);
    }
}

// Round 3
// 68.530 us; speedup vs baseline: 8.1915x; 1.2984x over previous
//
#include <hip/hip_runtime.h>

typedef __attribute__((ext_vector_type(8))) short bf16x8;
typedef __attribute__((ext_vector_type(4))) float f32x4;

#define HW_   252
#define PLANE 63504            // 252*252
#define NCH   32
#define PADW  262              // materialized padded extent (indices 0..261)
#define PROW  (PADW * NCH)     // elems per padded row = 8384
#define PIMG  ((size_t)PADW * PROW)
#define XPAD_ELEMS ((size_t)8 * PIMG)
#define WP_OFF_BYTES (XPAD_ELEMS * 2)          // 35,145,728 B
#define WS_NEED (WP_OFF_BYTES + 25600u * 2u)

__device__ __forceinline__ unsigned short f2bf(float f) {
    unsigned u = __builtin_bit_cast(unsigned, f);
    u += 0x7FFFu + ((u >> 16) & 1u);   // round-to-nearest-even
    return (unsigned short)(u >> 16);
}

// padded coord p (0..261) -> source row/col: circular mod 256, then reflect(p-2)
__device__ __forceinline__ int refl(int p) {
    int t = (p & 255) - 2;
    t = t < 0 ? -t : t;
    return t > 251 ? 502 - t : t;
}

// wp[t][o][ci] = bf16(w[o][ci][4-da][4-db]), t = da*5+db
__global__ void pack_w_kernel(const float* __restrict__ w, unsigned short* __restrict__ wp) {
    int e = blockIdx.x * 256 + threadIdx.x;   // [25][32][32]
    if (e >= 25600) return;
    int ci = e & 31;
    int o  = (e >> 5) & 31;
    int t  = e >> 10;
    int da = t / 5, db = t - da * 5;
    wp[e] = f2bf(w[((o * 32 + ci) * 5 + (4 - da)) * 5 + (4 - db)]);
}

// x[b][ci][h][w] fp32 -> xpad[b][r][c][ci] bf16 with pad folded in.
// One block per (b, padded row). Writes: 16B/lane, fully contiguous per wave.
__global__ __launch_bounds__(256) void pad_transpose(
    const float* __restrict__ x, unsigned short* __restrict__ xp)
{
    const int bid = blockIdx.x;           // b*262 + r
    const int b   = bid / PADW;
    const int r   = bid - b * PADW;
    const int mr  = refl(r);
    const float* src0 = x + (size_t)b * NCH * PLANE + (size_t)mr * HW_;
    unsigned short* dst0 = xp + (size_t)b * PIMG + (size_t)r * PROW;
    const int cig = threadIdx.x & 3;      // ci-group of 8
    const int cl  = threadIdx.x >> 2;     // 0..63 col-within-tile
    #pragma unroll
    for (int c0 = 0; c0 < PADW; c0 += 64) {
        int c = c0 + cl;
        if (c < PADW) {
            int mc = refl(c);
            unsigned short pk[8];
            #pragma unroll
            for (int q = 0; q < 8; ++q)
                pk[q] = f2bf(src0[(size_t)(cig * 8 + q) * PLANE + mc]);
            *reinterpret_cast<uint4*>(dst0 + (size_t)c * NCH + cig * 8) =
                *reinterpret_cast<const uint4*>(pk);
        }
    }
}

// Main conv: 16x16 pixel tile, 800 MFMAs/block after ONE barrier.
// Staging: 25 KB patch via global_load_lds (linear LDS dest, inverse-swizzled src).
__global__ __launch_bounds__(256) void conv_mfma_pad(
    const unsigned short* __restrict__ xp,
    const unsigned short* __restrict__ wp,
    float* __restrict__ out)
{
    __shared__ unsigned short xl[12800];   // [20 rows][20 cols][4 slots][8 ci] bf16

    const int tid  = threadIdx.x;
    const int orig = blockIdx.x;
    const int bid  = ((orig & 7) << 8) | (orig >> 3);  // XCD-bijective: b = orig&7
    const int b  = bid >> 8;
    const int rt = (bid >> 4) & 15;
    const int ct = bid & 15;
    const int i0 = rt * 16, j0 = ct * 16;

    const int lane = tid & 63;
    const int wid  = tid >> 6;

    // ---- stage 20x20x32 bf16 patch (1600 x 16B units) ----
    {
        const char* gb = (const char*)(xp +
            ((size_t)(b * PADW + i0 + 1) * PADW + (j0 + 1)) * NCH);
        #pragma unroll
        for (int it = 0; it < 7; ++it) {
            int unit = it * 256 + tid;
            if (unit < 1600) {                       // it=6: only wave 0 active (wave-uniform)
                int row = unit / 80;
                int u   = unit - row * 80;
                int col = u >> 2;
                int s   = u & 3;
                // LDS linear dest unit*16; source pre-swizzled so READ-side XOR matches
                const char* src = gb + (size_t)row * (PROW * 2) + col * 64
                                     + ((s ^ (col & 3)) << 4);
                char* ldst = ((char*)xl) + (it * 256 + wid * 64) * 16;
                __builtin_amdgcn_global_load_lds(
                    (const __attribute__((address_space(1))) void*)src,
                    (__attribute__((address_space(3))) void*)ldst,
                    16, 0, 0);
            }
        }
    }
    __syncthreads();

    const int lm    = lane & 15;   // o-within-16 (A) / pixel col (B,D)
    const int lg    = lane >> 4;   // k-group
    const int rbase = wid * 4;     // wave's 4 output rows

    f32x4 acc[4][2];
    #pragma unroll
    for (int rr = 0; rr < 4; ++rr) {
        acc[rr][0] = (f32x4){0.f, 0.f, 0.f, 0.f};
        acc[rr][1] = (f32x4){0.f, 0.f, 0.f, 0.f};
    }

    const char* wbase = (const char*)wp;
    const int afix = (lm << 6) + (lg << 4);
    const char* xlb = reinterpret_cast<const char*>(xl);

    #pragma unroll
    for (int da = 0; da < 5; ++da) {
        #pragma unroll
        for (int db = 0; db < 5; ++db) {
            const int t = da * 5 + db;
            bf16x8 a0 = *reinterpret_cast<const bf16x8*>(wbase + (t << 11) + afix);
            bf16x8 a1 = *reinterpret_cast<const bf16x8*>(wbase + (t << 11) + 1024 + afix);
            const int col  = lm + db;
            const int coff = (col << 6) + ((lg ^ (col & 3)) << 4);
            #pragma unroll
            for (int rr = 0; rr < 4; ++rr) {
                const int row = rbase + rr + da;
                bf16x8 bf = *reinterpret_cast<const bf16x8*>(xlb + row * 1280 + coff);
                acc[rr][0] = __builtin_amdgcn_mfma_f32_16x16x32_bf16(a0, bf, acc[rr][0], 0, 0, 0);
                acc[rr][1] = __builtin_amdgcn_mfma_f32_16x16x32_bf16(a1, bf, acc[rr][1], 0, 0, 0);
            }
        }
    }

    // writeback: o = mt*16 + lg*4 + q, pixel col = lm
    const int j = j0 + lm;
    #pragma unroll
    for (int rr = 0; rr < 4; ++rr) {
        const int i = i0 + rbase + rr;
        if (i < HW_ && j < HW_) {
            size_t rowoff = (size_t)(b * NCH) * PLANE + (size_t)i * HW_ + j;
            #pragma unroll
            for (int mt = 0; mt < 2; ++mt)
                #pragma unroll
                for (int q = 0; q < 4; ++q) {
                    int o = mt * 16 + lg * 4 + q;
                    out[rowoff + (size_t)o * PLANE] = acc[rr][mt][q];
                }
        }
    }
}

// ---------------- fallback (ws too small): R2 kernel, weights via LDS ----------------
__global__ __launch_bounds__(256) void conv_mfma_fb(
    const float* __restrict__ x,
    const float* __restrict__ w_raw,
    float* __restrict__ out)
{
    __shared__ unsigned short xl[12800];
    __shared__ unsigned short wl[25600];
    __shared__ int rmap[20], cmap[20];

    const int tid = threadIdx.x;
    const int bid = blockIdx.x;
    const int b  = bid >> 8;
    const int rt = (bid >> 4) & 15;
    const int ct = bid & 15;
    const int i0 = rt * 16, j0 = ct * 16;

    if (tid < 40) {
        int k    = tid < 20 ? tid : tid - 20;
        int base = tid < 20 ? i0  : j0;
        int r = (base + 1 + k) & 255;
        int t = r - 2;
        int m = t < 0 ? -t : (t > 251 ? 502 - t : t);
        if (tid < 20) rmap[k] = m; else cmap[k] = m;
    }
    for (int e = tid; e < 25600; e += 256) {
        int o   = e / 800;
        int rem = e - o * 800;
        int ci  = rem / 25;
        int kd  = rem - ci * 25;
        wl[(24 - kd) * 1024 + o * 32 + ci] = f2bf(w_raw[e]);
    }
    __syncthreads();

    for (int task = tid; task < 1600; task += 256) {
        int col = task % 20;
        int g   = (task / 20) & 3;
        int row = task / 80;
        const float* src = x + (size_t)(b * NCH + g * 8) * PLANE
                             + (size_t)rmap[row] * HW_ + cmap[col];
        unsigned short pk[8];
        #pragma unroll
        for (int q = 0; q < 8; ++q) pk[q] = f2bf(src[q * PLANE]);
        int off = ((row * 20 + col) << 6) + ((g ^ (col & 3)) << 4);
        *reinterpret_cast<uint4*>(reinterpret_cast<char*>(xl) + off)
            = *reinterpret_cast<const uint4*>(pk);
    }
    __syncthreads();

    const int lane  = tid & 63;
    const int wid   = tid >> 6;
    const int lm    = lane & 15;
    const int lg    = lane >> 4;
    const int rbase = wid * 4;

    f32x4 acc[4][2];
    #pragma unroll
    for (int rr = 0; rr < 4; ++rr) {
        acc[rr][0] = (f32x4){0.f, 0.f, 0.f, 0.f};
        acc[rr][1] = (f32x4){0.f, 0.f, 0.f, 0.f};
    }

    const char* wbase = (const char*)wl;
    const int afix = (lm << 6) + (lg << 4);
    const char* xlb = reinterpret_cast<const char*>(xl);

    #pragma unroll
    for (int da = 0; da < 5; ++da) {
        #pragma unroll
        for (int db = 0; db < 5; ++db) {
            const int t = da * 5 + db;
            bf16x8 a0 = *reinterpret_cast<const bf16x8*>(wbase + (t << 11) + afix);
            bf16x8 a1 = *reinterpret_cast<const bf16x8*>(wbase + (t << 11) + 1024 + afix);
            const int col  = lm + db;
            const int coff = (col << 6) + ((lg ^ (col & 3)) << 4);
            #pragma unroll
            for (int rr = 0; rr < 4; ++rr) {
                const int row = rbase + rr + da;
                bf16x8 bf = *reinterpret_cast<const bf16x8*>(xlb + row * 1280 + coff);
                acc[rr][0] = __builtin_amdgcn_mfma_f32_16x16x32_bf16(a0, bf, acc[rr][0], 0, 0, 0);
                acc[rr][1] = __builtin_amdgcn_mfma_f32_16x16x32_bf16(a1, bf, acc[rr][1], 0, 0, 0);
            }
        }
    }

    const int j = j0 + lm;
    #pragma unroll
    for (int rr = 0; rr < 4; ++rr) {
        const int i = i0 + rbase + rr;
        if (i < HW_ && j < HW_) {
            size_t rowoff = (size_t)(b * NCH) * PLANE + (size_t)i * HW_ + j;
            #pragma unroll
            for (int mt = 0; mt < 2; ++mt)
                #pragma unroll
                for (int q = 0; q < 4; ++q) {
                    int o = mt * 16 + lg * 4 + q;
                    out[rowoff + (size_t)o * PLANE] = acc[rr][mt][q];
                }
        }
    }
}

extern "C" void kernel_launch(void* const* d_in, const int* in_sizes, int n_in,
                              void* d_out, int out_size, void* d_ws, size_t ws_size,
                              hipStream_t stream) {
    const float* x = (const float*)d_in[0];
    const float* w = (const float*)d_in[1];
    float* out = (float*)d_out;

    if (ws_size >= WS_NEED) {
        unsigned short* xpad = (unsigned short*)d_ws;
        unsigned short* wp   = (unsigned short*)((char*)d_ws + WP_OFF_BYTES);
        hipLaunchKernelGGL(pack_w_kernel, dim3(100), dim3(256), 0, stream, w, wp);
        hipLaunchKernelGGL(pad_transpose, dim3(8 * PADW), dim3(256), 0, stream, x, xpad);
        hipLaunchKernelGGL(conv_mfma_pad, dim3(2048), dim3(256), 0, stream,
                           (const unsigned short*)xpad, (const unsigned short*)wp, out);
    } else {
        hipLaunchKernelGGL(conv_mfma_fb, dim3(2048), dim3(256), 0, stream, x, w, out);
    }
}

// Round 4
// 59.569 us; speedup vs baseline: 9.4238x; 1.1504x over previous
//
#include <hip/hip_runtime.h>

typedef __attribute__((ext_vector_type(8))) short bf16x8;
typedef __attribute__((ext_vector_type(4))) float f32x4;

#define HW_   252
#define PLANE 63504            // 252*252
#define NCH   32
#define PADW  262              // materialized padded extent
#define PROW  (PADW * NCH)     // elems per padded row = 8384
#define PIMG  ((size_t)PADW * PROW)
#define XPAD_ELEMS ((size_t)8 * PIMG)
#define WP_OFF_BYTES (XPAD_ELEMS * 2)
#define WS_NEED (WP_OFF_BYTES + 25600u * 2u)

__device__ __forceinline__ unsigned short f2bf(float f) {
    unsigned u = __builtin_bit_cast(unsigned, f);
    u += 0x7FFFu + ((u >> 16) & 1u);   // round-to-nearest-even
    return (unsigned short)(u >> 16);
}

// padded coord p (0..261) -> source index: circular mod 256, then reflect(p-2)
__device__ __forceinline__ int refl(int p) {
    int t = (p & 255) - 2;
    t = t < 0 ? -t : t;
    return t > 251 ? 502 - t : t;
}

// wp[t][o][ci] = bf16(w[o][ci][4-da][4-db]), t = da*5+db
__global__ void pack_w_kernel(const float* __restrict__ w, unsigned short* __restrict__ wp) {
    int e = blockIdx.x * 256 + threadIdx.x;   // [25][32][32]
    if (e >= 25600) return;
    int ci = e & 31;
    int o  = (e >> 5) & 31;
    int t  = e >> 10;
    int da = t / 5, db = t - da * 5;
    wp[e] = f2bf(w[((o * 32 + ci) * 5 + (4 - da)) * 5 + (4 - db)]);
}

// x[b][ci][h][w] fp32 -> xpad[b][r][c][ci] bf16, pad folded in.
__global__ __launch_bounds__(256) void pad_transpose(
    const float* __restrict__ x, unsigned short* __restrict__ xp)
{
    const int bid = blockIdx.x;           // b*262 + r
    const int b   = bid / PADW;
    const int r   = bid - b * PADW;
    const int mr  = refl(r);
    const float* src0 = x + (size_t)b * NCH * PLANE + (size_t)mr * HW_;
    unsigned short* dst0 = xp + (size_t)b * PIMG + (size_t)r * PROW;
    const int cig = threadIdx.x & 3;      // ci-group of 8
    const int cl  = threadIdx.x >> 2;     // col-within-64-tile
    #pragma unroll
    for (int c0 = 0; c0 < PADW; c0 += 64) {
        int c = c0 + cl;
        if (c < PADW) {
            int mc = refl(c);
            unsigned short pk[8];
            #pragma unroll
            for (int q = 0; q < 8; ++q)
                pk[q] = f2bf(src0[(size_t)(cig * 8 + q) * PLANE + mc]);
            *reinterpret_cast<uint4*>(dst0 + (size_t)c * NCH + cig * 8) =
                *reinterpret_cast<const uint4*>(pk);
        }
    }
}

// Conv: block = 32 rows x 16 cols, 4 waves (8 rows each), patch 36x20x32 bf16.
// Shift-structured loop: one B ds_read feeds up to 5 taps (da) -> LDS traffic /3.3.
__global__ __launch_bounds__(256, 3) void conv_mfma_v3(
    const unsigned short* __restrict__ xp,
    const unsigned short* __restrict__ wp,
    float* __restrict__ out)
{
    __shared__ unsigned short xl[36 * 20 * 32];   // 46080 B, linear [pr][col][ci]

    const int tid  = threadIdx.x;
    const int orig = blockIdx.x;                  // 1024 blocks
    const int bid  = ((orig & 7) << 7) | (orig >> 3);   // XCD-bijective: b = orig&7
    const int b  = bid >> 7;          // 0..7
    const int rt = (bid >> 4) & 7;    // 0..7
    const int ct = bid & 15;          // 0..15
    const int i0 = rt * 32, j0 = ct * 16;

    const int lane = tid & 63;
    const int wid  = tid >> 6;

    // ---- stage 36x20x32 bf16 (2880 x 16B units), fully linear both sides ----
    {
        const char* gb = (const char*)(xp +
            ((size_t)(b * PADW + i0 + 1) * PADW + (j0 + 1)) * NCH);
        #pragma unroll
        for (int it = 0; it < 12; ++it) {
            int unit = it * 256 + tid;
            if (unit < 2880) {                    // it=11: wave 0 only (wave-uniform)
                int pr = unit / 80;               // 20 cols * 64B = 80 units/row
                int u  = unit - pr * 80;
                const char* src = gb + (size_t)pr * (PROW * 2) + u * 16;
                char* ldst = ((char*)xl) + (it * 256 + wid * 64) * 16;
                __builtin_amdgcn_global_load_lds(
                    (const __attribute__((address_space(1))) void*)src,
                    (__attribute__((address_space(3))) void*)ldst,
                    16, 0, 0);
            }
        }
    }
    __syncthreads();

    const int lm   = lane & 15;    // o-within-16 (A) / pixel col (B,D)
    const int lg   = lane >> 4;    // k-group
    const int rowb = wid * 8;      // wave's first local output row

    const char* xlb = reinterpret_cast<const char*>(xl);
    const char* wb  = reinterpret_cast<const char*>(wp);
    const int afix  = (lm << 6) + (lg << 4);
    const int j     = j0 + lm;

    #pragma unroll
    for (int mt = 0; mt < 2; ++mt) {
        f32x4 acc[8];
        #pragma unroll
        for (int r = 0; r < 8; ++r) acc[r] = (f32x4){0.f, 0.f, 0.f, 0.f};

        #pragma unroll
        for (int db = 0; db < 5; ++db) {
            bf16x8 a[5];
            #pragma unroll
            for (int da = 0; da < 5; ++da)
                a[da] = *reinterpret_cast<const bf16x8*>(
                    wb + ((da * 5 + db) << 11) + (mt << 10) + afix);

            #pragma unroll
            for (int l = 0; l < 12; ++l) {
                // patch row rowb+l, cols lm+db: contiguous 1KB per wave -> conflict-free
                bf16x8 bf = *reinterpret_cast<const bf16x8*>(
                    xlb + (rowb + l) * 1280 + ((lm + db) << 6) + (lg << 4));
                #pragma unroll
                for (int da = 0; da < 5; ++da) {
                    const int r = l - da;
                    if (r >= 0 && r < 8)
                        acc[r] = __builtin_amdgcn_mfma_f32_16x16x32_bf16(
                            a[da], bf, acc[r], 0, 0, 0);
                }
            }
        }

        // store this mt half: o = mt*16 + lg*4 + q, col = lm
        #pragma unroll
        for (int r = 0; r < 8; ++r) {
            const int i = i0 + rowb + r;
            if (i < HW_ && j < HW_) {
                size_t rowoff = ((size_t)(b * NCH + mt * 16 + lg * 4)) * PLANE
                              + (size_t)i * HW_ + j;
                #pragma unroll
                for (int q = 0; q < 4; ++q)
                    out[rowoff + (size_t)q * PLANE] = acc[r][q];
            }
        }
    }
}

// ---------------- fallback (ws too small): R2-style single kernel ----------------
__global__ __launch_bounds__(256) void conv_mfma_fb(
    const float* __restrict__ x,
    const float* __restrict__ w_raw,
    float* __restrict__ out)
{
    __shared__ unsigned short xl[12800];
    __shared__ unsigned short wl[25600];
    __shared__ int rmap[20], cmap[20];

    const int tid = threadIdx.x;
    const int bid = blockIdx.x;
    const int b  = bid >> 8;
    const int rt = (bid >> 4) & 15;
    const int ct = bid & 15;
    const int i0 = rt * 16, j0 = ct * 16;

    if (tid < 40) {
        int k    = tid < 20 ? tid : tid - 20;
        int base = tid < 20 ? i0  : j0;
        int r = (base + 1 + k) & 255;
        int t = r - 2;
        int m = t < 0 ? -t : (t > 251 ? 502 - t : t);
        if (tid < 20) rmap[k] = m; else cmap[k] = m;
    }
    for (int e = tid; e < 25600; e += 256) {
        int o   = e / 800;
        int rem = e - o * 800;
        int ci  = rem / 25;
        int kd  = rem - ci * 25;
        wl[(24 - kd) * 1024 + o * 32 + ci] = f2bf(w_raw[e]);
    }
    __syncthreads();

    for (int task = tid; task < 1600; task += 256) {
        int col = task % 20;
        int g   = (task / 20) & 3;
        int row = task / 80;
        const float* src = x + (size_t)(b * NCH + g * 8) * PLANE
                             + (size_t)rmap[row] * HW_ + cmap[col];
        unsigned short pk[8];
        #pragma unroll
        for (int q = 0; q < 8; ++q) pk[q] = f2bf(src[q * PLANE]);
        int off = ((row * 20 + col) << 6) + ((g ^ (col & 3)) << 4);
        *reinterpret_cast<uint4*>(reinterpret_cast<char*>(xl) + off)
            = *reinterpret_cast<const uint4*>(pk);
    }
    __syncthreads();

    const int lane  = tid & 63;
    const int wid   = tid >> 6;
    const int lm    = lane & 15;
    const int lg    = lane >> 4;
    const int rbase = wid * 4;

    f32x4 acc[4][2];
    #pragma unroll
    for (int rr = 0; rr < 4; ++rr) {
        acc[rr][0] = (f32x4){0.f, 0.f, 0.f, 0.f};
        acc[rr][1] = (f32x4){0.f, 0.f, 0.f, 0.f};
    }

    const char* wbase = (const char*)wl;
    const int afix = (lm << 6) + (lg << 4);
    const char* xlb = reinterpret_cast<const char*>(xl);

    #pragma unroll
    for (int da = 0; da < 5; ++da) {
        #pragma unroll
        for (int db = 0; db < 5; ++db) {
            const int t = da * 5 + db;
            bf16x8 a0 = *reinterpret_cast<const bf16x8*>(wbase + (t << 11) + afix);
            bf16x8 a1 = *reinterpret_cast<const bf16x8*>(wbase + (t << 11) + 1024 + afix);
            const int col  = lm + db;
            const int coff = (col << 6) + ((lg ^ (col & 3)) << 4);
            #pragma unroll
            for (int rr = 0; rr < 4; ++rr) {
                const int row = rbase + rr + da;
                bf16x8 bf = *reinterpret_cast<const bf16x8*>(xlb + row * 1280 + coff);
                acc[rr][0] = __builtin_amdgcn_mfma_f32_16x16x32_bf16(a0, bf, acc[rr][0], 0, 0, 0);
                acc[rr][1] = __builtin_amdgcn_mfma_f32_16x16x32_bf16(a1, bf, acc[rr][1], 0, 0, 0);
            }
        }
    }

    const int j = j0 + lm;
    #pragma unroll
    for (int rr = 0; rr < 4; ++rr) {
        const int i = i0 + rbase + rr;
        if (i < HW_ && j < HW_) {
            size_t rowoff = (size_t)(b * NCH) * PLANE + (size_t)i * HW_ + j;
            #pragma unroll
            for (int mt = 0; mt < 2; ++mt)
                #pragma unroll
                for (int q = 0; q < 4; ++q) {
                    int o = mt * 16 + lg * 4 + q;
                    out[rowoff + (size_t)o * PLANE] = acc[rr][mt][q];
                }
        }
    }
}

extern "C" void kernel_launch(void* const* d_in, const int* in_sizes, int n_in,
                              void* d_out, int out_size, void* d_ws, size_t ws_size,
                              hipStream_t stream) {
    const float* x = (const float*)d_in[0];
    const float* w = (const float*)d_in[1];
    float* out = (float*)d_out;

    if (ws_size >= WS_NEED) {
        unsigned short* xpad = (unsigned short*)d_ws;
        unsigned short* wp   = (unsigned short*)((char*)d_ws + WP_OFF_BYTES);
        hipLaunchKernelGGL(pack_w_kernel, dim3(100), dim3(256), 0, stream, w, wp);
        hipLaunchKernelGGL(pad_transpose, dim3(8 * PADW), dim3(256), 0, stream, x, xpad);
        hipLaunchKernelGGL(conv_mfma_v3, dim3(1024), dim3(256), 0, stream,
                           (const unsigned short*)xpad, (const unsigned short*)wp, out);
    } else {
        hipLaunchKernelGGL(conv_mfma_fb, dim3(2048), dim3(256), 0, stream, x, w, out);
    }
}

// Round 5
// 55.111 us; speedup vs baseline: 10.1861x; 1.0809x over previous
//
#include <hip/hip_runtime.h>

typedef __attribute__((ext_vector_type(8))) short bf16x8;
typedef __attribute__((ext_vector_type(4))) float f32x4;

#define HW_   252
#define PLANE 63504            // 252*252
#define NCH   32
#define PADW  262              // materialized padded extent
#define PROW  (PADW * NCH)     // elems per padded row = 8384
#define PIMG  ((size_t)PADW * PROW)
#define XPAD_ELEMS ((size_t)8 * PIMG)
#define WP_OFF_BYTES (XPAD_ELEMS * 2)
#define WS_NEED (WP_OFF_BYTES + 25600u * 2u)

__device__ __forceinline__ unsigned short f2bf(float f) {
    unsigned u = __builtin_bit_cast(unsigned, f);
    u += 0x7FFFu + ((u >> 16) & 1u);   // round-to-nearest-even
    return (unsigned short)(u >> 16);
}

// padded coord p (0..261) -> source index: circular mod 256, then reflect(p-2)
__device__ __forceinline__ int refl(int p) {
    int t = (p & 255) - 2;
    t = t < 0 ? -t : t;
    return t > 251 ? 502 - t : t;
}

// Fused pad+transpose+weight-pack.
// Blocks [0, 8*262): one (b, padded row r). Coalesced float4 reads of all 32
// plane-rows -> LDS -> contiguous uint4 bf16 writes of xpad[b][r][c][ci].
// Blocks [8*262, 8*262+100): weight pack wp[t][o][ci] = bf16(w[o][ci][4-da][4-db]).
__global__ __launch_bounds__(256) void pad_pack(
    const float* __restrict__ x, unsigned short* __restrict__ xp,
    const float* __restrict__ w, unsigned short* __restrict__ wp)
{
    const int bid = blockIdx.x;
    const int tid = threadIdx.x;

    if (bid >= 8 * PADW) {                 // ---- weight pack ----
        int e = (bid - 8 * PADW) * 256 + tid;   // [25][32][32]
        int ci = e & 31;
        int o  = (e >> 5) & 31;
        int t  = e >> 10;
        int da = t / 5, db = t - da * 5;
        wp[e] = f2bf(w[((o * 32 + ci) * 5 + (4 - da)) * 5 + (4 - db)]);
        return;
    }

    __shared__ unsigned short s[32][260];  // [ci][src col], stride 260 (conflict-light)

    const int b  = bid / PADW;
    const int r  = bid - b * PADW;
    const int mr = refl(r);
    const float* src0 = x + (size_t)b * NCH * PLANE + (size_t)mr * HW_;

    // read phase: thread (ci = tid>>3, part = tid&7) streams float4s of one plane row
    {
        const int ci   = tid >> 3;
        const int part = tid & 7;
        const float* sp = src0 + (size_t)ci * PLANE;
        #pragma unroll
        for (int c4 = 0; c4 < 8; ++c4) {
            int col = part * 32 + c4 * 4;
            if (col < HW_) {
                float4 v = *reinterpret_cast<const float4*>(sp + col);
                s[ci][col + 0] = f2bf(v.x);
                s[ci][col + 1] = f2bf(v.y);
                s[ci][col + 2] = f2bf(v.z);
                s[ci][col + 3] = f2bf(v.w);
            }
        }
    }
    __syncthreads();

    // write phase: thread (cpart = tid>>2, g = tid&3) emits xpad[.][c][g*8..g*8+7]
    unsigned short* dst0 = xp + (size_t)b * PIMG + (size_t)r * PROW;
    const int cpart = tid >> 2;
    const int g     = tid & 3;
    #pragma unroll
    for (int cb = 0; cb < PADW; cb += 64) {
        int c = cb + cpart;
        if (c < PADW) {
            int mc = refl(c);
            unsigned short pk[8];
            #pragma unroll
            for (int q = 0; q < 8; ++q) pk[q] = s[g * 8 + q][mc];
            *reinterpret_cast<uint4*>(dst0 + (size_t)c * NCH + g * 8) =
                *reinterpret_cast<const uint4*>(pk);
        }
    }
}

// Conv: block = 28 rows x 16 cols, 4 waves (7 rows each), patch 32x20x32 bf16
// = exactly 40 KB LDS -> 4 blocks/CU. 252 = 9*28 (exact row tiling).
// Shift-structured: one B ds_read feeds up to 5 da-taps.
__global__ __launch_bounds__(256, 4) void conv_mfma_v4(
    const unsigned short* __restrict__ xp,
    const unsigned short* __restrict__ wp,
    float* __restrict__ out)
{
    __shared__ unsigned short xl[32 * 20 * 32];   // 40960 B, linear [pr][col][ci]

    const int tid  = threadIdx.x;
    const int orig = blockIdx.x;                  // 1152 blocks = 8 XCD * 144
    const int b    = orig & 7;                    // XCD-bijective: image b per XCD
    const int idx  = orig >> 3;                   // 0..143
    const int rt   = idx >> 4;                    // 0..8
    const int ct   = idx & 15;                    // 0..15
    const int i0 = rt * 28, j0 = ct * 16;

    const int lane = tid & 63;
    const int wid  = tid >> 6;

    // ---- stage 32x20x32 bf16 (2560 x 16B units, exactly 10 iters) ----
    {
        const char* gb = (const char*)(xp +
            ((size_t)b * PIMG + (size_t)(i0 + 1) * PROW + (size_t)(j0 + 1) * NCH));
        #pragma unroll
        for (int it = 0; it < 10; ++it) {
            int unit = it * 256 + tid;
            int pr   = unit / 80;                 // 20 cols * 64B = 80 units/row
            int u    = unit - pr * 80;
            const char* src = gb + (size_t)pr * (PROW * 2) + u * 16;
            char* ldst = ((char*)xl) + (it * 4096 + wid * 1024);  // wave-uniform
            __builtin_amdgcn_global_load_lds(
                (const __attribute__((address_space(1))) void*)src,
                (__attribute__((address_space(3))) void*)ldst,
                16, 0, 0);
        }
    }
    __syncthreads();

    const int lm   = lane & 15;    // o-within-16 (A) / pixel col (B,D)
    const int lg   = lane >> 4;    // k-group
    const int rowb = wid * 7;      // wave's first local output row

    const char* xlb = reinterpret_cast<const char*>(xl);
    const char* wb  = reinterpret_cast<const char*>(wp);
    const int afix  = (lm << 6) + (lg << 4);
    const int j     = j0 + lm;

    #pragma unroll
    for (int mt = 0; mt < 2; ++mt) {
        f32x4 acc[7];
        #pragma unroll
        for (int r = 0; r < 7; ++r) acc[r] = (f32x4){0.f, 0.f, 0.f, 0.f};

        #pragma unroll
        for (int db = 0; db < 5; ++db) {
            bf16x8 a[5];
            #pragma unroll
            for (int da = 0; da < 5; ++da)
                a[da] = *reinterpret_cast<const bf16x8*>(
                    wb + ((da * 5 + db) << 11) + (mt << 10) + afix);

            #pragma unroll
            for (int l = 0; l < 11; ++l) {
                // patch row rowb+l, cols lm+db: contiguous 1KB per wave, conflict-free
                bf16x8 bf = *reinterpret_cast<const bf16x8*>(
                    xlb + (rowb + l) * 1280 + ((lm + db) << 6) + (lg << 4));
                #pragma unroll
                for (int da = 0; da < 5; ++da) {
                    const int r = l - da;
                    if (r >= 0 && r < 7)
                        acc[r] = __builtin_amdgcn_mfma_f32_16x16x32_bf16(
                            a[da], bf, acc[r], 0, 0, 0);
                }
            }
        }

        // store this mt half: o = mt*16 + lg*4 + q, col = lm (rows always in-bounds)
        #pragma unroll
        for (int r = 0; r < 7; ++r) {
            const int i = i0 + rowb + r;
            if (j < HW_) {
                size_t rowoff = ((size_t)(b * NCH + mt * 16 + lg * 4)) * PLANE
                              + (size_t)i * HW_ + j;
                #pragma unroll
                for (int q = 0; q < 4; ++q)
                    out[rowoff + (size_t)q * PLANE] = acc[r][q];
            }
        }
    }
}

// ---------------- fallback (ws too small): R2-style single kernel ----------------
__global__ __launch_bounds__(256) void conv_mfma_fb(
    const float* __restrict__ x,
    const float* __restrict__ w_raw,
    float* __restrict__ out)
{
    __shared__ unsigned short xl[12800];
    __shared__ unsigned short wl[25600];
    __shared__ int rmap[20], cmap[20];

    const int tid = threadIdx.x;
    const int bid = blockIdx.x;
    const int b  = bid >> 8;
    const int rt = (bid >> 4) & 15;
    const int ct = bid & 15;
    const int i0 = rt * 16, j0 = ct * 16;

    if (tid < 40) {
        int k    = tid < 20 ? tid : tid - 20;
        int base = tid < 20 ? i0  : j0;
        int r = (base + 1 + k) & 255;
        int t = r - 2;
        int m = t < 0 ? -t : (t > 251 ? 502 - t : t);
        if (tid < 20) rmap[k] = m; else cmap[k] = m;
    }
    for (int e = tid; e < 25600; e += 256) {
        int o   = e / 800;
        int rem = e - o * 800;
        int ci  = rem / 25;
        int kd  = rem - ci * 25;
        wl[(24 - kd) * 1024 + o * 32 + ci] = f2bf(w_raw[e]);
    }
    __syncthreads();

    for (int task = tid; task < 1600; task += 256) {
        int col = task % 20;
        int g   = (task / 20) & 3;
        int row = task / 80;
        const float* src = x + (size_t)(b * NCH + g * 8) * PLANE
                             + (size_t)rmap[row] * HW_ + cmap[col];
        unsigned short pk[8];
        #pragma unroll
        for (int q = 0; q < 8; ++q) pk[q] = f2bf(src[q * PLANE]);
        int off = ((row * 20 + col) << 6) + ((g ^ (col & 3)) << 4);
        *reinterpret_cast<uint4*>(reinterpret_cast<char*>(xl) + off)
            = *reinterpret_cast<const uint4*>(pk);
    }
    __syncthreads();

    const int lane  = tid & 63;
    const int wid   = tid >> 6;
    const int lm    = lane & 15;
    const int lg    = lane >> 4;
    const int rbase = wid * 4;

    f32x4 acc[4][2];
    #pragma unroll
    for (int rr = 0; rr < 4; ++rr) {
        acc[rr][0] = (f32x4){0.f, 0.f, 0.f, 0.f};
        acc[rr][1] = (f32x4){0.f, 0.f, 0.f, 0.f};
    }

    const char* wbase = (const char*)wl;
    const int afix = (lm << 6) + (lg << 4);
    const char* xlb = reinterpret_cast<const char*>(xl);

    #pragma unroll
    for (int da = 0; da < 5; ++da) {
        #pragma unroll
        for (int db = 0; db < 5; ++db) {
            const int t = da * 5 + db;
            bf16x8 a0 = *reinterpret_cast<const bf16x8*>(wbase + (t << 11) + afix);
            bf16x8 a1 = *reinterpret_cast<const bf16x8*>(wbase + (t << 11) + 1024 + afix);
            const int col  = lm + db;
            const int coff = (col << 6) + ((lg ^ (col & 3)) << 4);
            #pragma unroll
            for (int rr = 0; rr < 4; ++rr) {
                const int row = rbase + rr + da;
                bf16x8 bf = *reinterpret_cast<const bf16x8*>(xlb + row * 1280 + coff);
                acc[rr][0] = __builtin_amdgcn_mfma_f32_16x16x32_bf16(a0, bf, acc[rr][0], 0, 0, 0);
                acc[rr][1] = __builtin_amdgcn_mfma_f32_16x16x32_bf16(a1, bf, acc[rr][1], 0, 0, 0);
            }
        }
    }

    const int j = j0 + lm;
    #pragma unroll
    for (int rr = 0; rr < 4; ++rr) {
        const int i = i0 + rbase + rr;
        if (i < HW_ && j < HW_) {
            size_t rowoff = (size_t)(b * NCH) * PLANE + (size_t)i * HW_ + j;
            #pragma unroll
            for (int mt = 0; mt < 2; ++mt)
                #pragma unroll
                for (int q = 0; q < 4; ++q) {
                    int o = mt * 16 + lg * 4 + q;
                    out[rowoff + (size_t)o * PLANE] = acc[rr][mt][q];
                }
        }
    }
}

extern "C" void kernel_launch(void* const* d_in, const int* in_sizes, int n_in,
                              void* d_out, int out_size, void* d_ws, size_t ws_size,
                              hipStream_t stream) {
    const float* x = (const float*)d_in[0];
    const float* w = (const float*)d_in[1];
    float* out = (float*)d_out;

    if (ws_size >= WS_NEED) {
        unsigned short* xpad = (unsigned short*)d_ws;
        unsigned short* wp   = (unsigned short*)((char*)d_ws + WP_OFF_BYTES);
        hipLaunchKernelGGL(pad_pack, dim3(8 * PADW + 100), dim3(256), 0, stream,
                           x, xpad, w, wp);
        hipLaunchKernelGGL(conv_mfma_v4, dim3(1152), dim3(256), 0, stream,
                           (const unsigned short*)xpad, (const unsigned short*)wp, out);
    } else {
        hipLaunchKernelGGL(conv_mfma_fb, dim3(2048), dim3(256), 0, stream, x, w, out);
    }
}

// Round 6
// 53.929 us; speedup vs baseline: 10.4094x; 1.0219x over previous
//
#include <hip/hip_runtime.h>

typedef __attribute__((ext_vector_type(8))) short bf16x8;
typedef __attribute__((ext_vector_type(4))) float f32x4;

#define HW_   252
#define PLANE 63504            // 252*252
#define NCH   32
#define PADW  262              // materialized padded extent
#define PROW  (PADW * NCH)     // elems per padded row = 8384
#define PIMG  ((size_t)PADW * PROW)
#define XPAD_ELEMS ((size_t)8 * PIMG)
#define WP_OFF_BYTES (XPAD_ELEMS * 2)
#define WS_NEED (WP_OFF_BYTES + 25600u * 2u)

__device__ __forceinline__ unsigned short f2bf(float f) {
    unsigned u = __builtin_bit_cast(unsigned, f);
    u += 0x7FFFu + ((u >> 16) & 1u);   // round-to-nearest-even
    return (unsigned short)(u >> 16);
}

// padded coord p (0..261) -> source index: circular mod 256, then reflect(p-2)
__device__ __forceinline__ int refl(int p) {
    int t = (p & 255) - 2;
    t = t < 0 ? -t : t;
    return t > 251 ? 502 - t : t;
}

// Fused pad+transpose+weight-pack (unchanged from R5 — near its BW floor).
__global__ __launch_bounds__(256) void pad_pack(
    const float* __restrict__ x, unsigned short* __restrict__ xp,
    const float* __restrict__ w, unsigned short* __restrict__ wp)
{
    const int bid = blockIdx.x;
    const int tid = threadIdx.x;

    if (bid >= 8 * PADW) {                 // ---- weight pack ----
        int e = (bid - 8 * PADW) * 256 + tid;   // [25][32][32]
        int ci = e & 31;
        int o  = (e >> 5) & 31;
        int t  = e >> 10;
        int da = t / 5, db = t - da * 5;
        wp[e] = f2bf(w[((o * 32 + ci) * 5 + (4 - da)) * 5 + (4 - db)]);
        return;
    }

    __shared__ unsigned short s[32][260];  // [ci][src col]

    const int b  = bid / PADW;
    const int r  = bid - b * PADW;
    const int mr = refl(r);
    const float* src0 = x + (size_t)b * NCH * PLANE + (size_t)mr * HW_;

    {
        const int ci   = tid >> 3;
        const int part = tid & 7;
        const float* sp = src0 + (size_t)ci * PLANE;
        #pragma unroll
        for (int c4 = 0; c4 < 8; ++c4) {
            int col = part * 32 + c4 * 4;
            if (col < HW_) {
                float4 v = *reinterpret_cast<const float4*>(sp + col);
                s[ci][col + 0] = f2bf(v.x);
                s[ci][col + 1] = f2bf(v.y);
                s[ci][col + 2] = f2bf(v.z);
                s[ci][col + 3] = f2bf(v.w);
            }
        }
    }
    __syncthreads();

    unsigned short* dst0 = xp + (size_t)b * PIMG + (size_t)r * PROW;
    const int cpart = tid >> 2;
    const int g     = tid & 3;
    #pragma unroll
    for (int cb = 0; cb < PADW; cb += 64) {
        int c = cb + cpart;
        if (c < PADW) {
            int mc = refl(c);
            unsigned short pk[8];
            #pragma unroll
            for (int q = 0; q < 8; ++q) pk[q] = s[g * 8 + q][mc];
            *reinterpret_cast<uint4*>(dst0 + (size_t)c * NCH + g * 8) =
                *reinterpret_cast<const uint4*>(pk);
        }
    }
}

// Conv v5: 28 rows x 16 cols per block, 4 waves x 7 rows, 40 KB patch, 4 blk/CU.
// mt halves MERGED: one B ds_read feeds up to 10 MFMAs (2 mt x 5 da).
// LDS reads/wave: 55 (was 110).
__global__ __launch_bounds__(256, 4) void conv_mfma_v5(
    const unsigned short* __restrict__ xp,
    const unsigned short* __restrict__ wp,
    float* __restrict__ out)
{
    __shared__ unsigned short xl[32 * 20 * 32];   // 40960 B, linear [pr][col][ci]

    const int tid  = threadIdx.x;
    const int orig = blockIdx.x;                  // 1152 blocks = 8 XCD * 144
    const int b    = orig & 7;                    // XCD-bijective: image b per XCD
    const int idx  = orig >> 3;                   // 0..143
    const int rt   = idx >> 4;                    // 0..8
    const int ct   = idx & 15;                    // 0..15
    const int i0 = rt * 28, j0 = ct * 16;

    const int lane = tid & 63;
    const int wid  = tid >> 6;

    // ---- stage 32x20x32 bf16 (2560 x 16B units, exactly 10 iters) ----
    {
        const char* gb = (const char*)(xp +
            ((size_t)b * PIMG + (size_t)(i0 + 1) * PROW + (size_t)(j0 + 1) * NCH));
        #pragma unroll
        for (int it = 0; it < 10; ++it) {
            int unit = it * 256 + tid;
            int pr   = unit / 80;                 // 20 cols * 64B = 80 units/row
            int u    = unit - pr * 80;
            const char* src = gb + (size_t)pr * (PROW * 2) + u * 16;
            char* ldst = ((char*)xl) + (it * 4096 + wid * 1024);  // wave-uniform
            __builtin_amdgcn_global_load_lds(
                (const __attribute__((address_space(1))) void*)src,
                (__attribute__((address_space(3))) void*)ldst,
                16, 0, 0);
        }
    }
    __syncthreads();

    const int lm   = lane & 15;    // o-within-16 (A) / pixel col (B,D)
    const int lg   = lane >> 4;    // k-group
    const int rowb = wid * 7;      // wave's first local output row

    const char* xlb = reinterpret_cast<const char*>(xl);
    const char* wb  = reinterpret_cast<const char*>(wp);
    const int afix  = (lm << 6) + (lg << 4);
    const int j     = j0 + lm;

    f32x4 acc[7][2];
    #pragma unroll
    for (int r = 0; r < 7; ++r) {
        acc[r][0] = (f32x4){0.f, 0.f, 0.f, 0.f};
        acc[r][1] = (f32x4){0.f, 0.f, 0.f, 0.f};
    }

    #pragma unroll
    for (int db = 0; db < 5; ++db) {
        bf16x8 a[5][2];
        #pragma unroll
        for (int da = 0; da < 5; ++da) {
            const char* ap = wb + ((da * 5 + db) << 11) + afix;
            a[da][0] = *reinterpret_cast<const bf16x8*>(ap);
            a[da][1] = *reinterpret_cast<const bf16x8*>(ap + 1024);
        }

        #pragma unroll
        for (int l = 0; l < 11; ++l) {
            // patch row rowb+l, cols lm+db: contiguous 1KB per wave, conflict-free
            bf16x8 bf = *reinterpret_cast<const bf16x8*>(
                xlb + (rowb + l) * 1280 + ((lm + db) << 6) + (lg << 4));
            #pragma unroll
            for (int da = 0; da < 5; ++da) {
                const int r = l - da;
                if (r >= 0 && r < 7) {
                    acc[r][0] = __builtin_amdgcn_mfma_f32_16x16x32_bf16(
                        a[da][0], bf, acc[r][0], 0, 0, 0);
                    acc[r][1] = __builtin_amdgcn_mfma_f32_16x16x32_bf16(
                        a[da][1], bf, acc[r][1], 0, 0, 0);
                }
            }
        }
    }

    // store: o = mt*16 + lg*4 + q, col = lm (rows always in-bounds; 252=9*28)
    #pragma unroll
    for (int r = 0; r < 7; ++r) {
        const int i = i0 + rowb + r;
        if (j < HW_) {
            #pragma unroll
            for (int mt = 0; mt < 2; ++mt) {
                size_t rowoff = ((size_t)(b * NCH + mt * 16 + lg * 4)) * PLANE
                              + (size_t)i * HW_ + j;
                #pragma unroll
                for (int q = 0; q < 4; ++q)
                    out[rowoff + (size_t)q * PLANE] = acc[r][mt][q];
            }
        }
    }
}

// ---------------- fallback (ws too small): R2-style single kernel ----------------
__global__ __launch_bounds__(256) void conv_mfma_fb(
    const float* __restrict__ x,
    const float* __restrict__ w_raw,
    float* __restrict__ out)
{
    __shared__ unsigned short xl[12800];
    __shared__ unsigned short wl[25600];
    __shared__ int rmap[20], cmap[20];

    const int tid = threadIdx.x;
    const int bid = blockIdx.x;
    const int b  = bid >> 8;
    const int rt = (bid >> 4) & 15;
    const int ct = bid & 15;
    const int i0 = rt * 16, j0 = ct * 16;

    if (tid < 40) {
        int k    = tid < 20 ? tid : tid - 20;
        int base = tid < 20 ? i0  : j0;
        int r = (base + 1 + k) & 255;
        int t = r - 2;
        int m = t < 0 ? -t : (t > 251 ? 502 - t : t);
        if (tid < 20) rmap[k] = m; else cmap[k] = m;
    }
    for (int e = tid; e < 25600; e += 256) {
        int o   = e / 800;
        int rem = e - o * 800;
        int ci  = rem / 25;
        int kd  = rem - ci * 25;
        wl[(24 - kd) * 1024 + o * 32 + ci] = f2bf(w_raw[e]);
    }
    __syncthreads();

    for (int task = tid; task < 1600; task += 256) {
        int col = task % 20;
        int g   = (task / 20) & 3;
        int row = task / 80;
        const float* src = x + (size_t)(b * NCH + g * 8) * PLANE
                             + (size_t)rmap[row] * HW_ + cmap[col];
        unsigned short pk[8];
        #pragma unroll
        for (int q = 0; q < 8; ++q) pk[q] = f2bf(src[q * PLANE]);
        int off = ((row * 20 + col) << 6) + ((g ^ (col & 3)) << 4);
        *reinterpret_cast<uint4*>(reinterpret_cast<char*>(xl) + off)
            = *reinterpret_cast<const uint4*>(pk);
    }
    __syncthreads();

    const int lane  = tid & 63;
    const int wid   = tid >> 6;
    const int lm    = lane & 15;
    const int lg    = lane >> 4;
    const int rbase = wid * 4;

    f32x4 acc[4][2];
    #pragma unroll
    for (int rr = 0; rr < 4; ++rr) {
        acc[rr][0] = (f32x4){0.f, 0.f, 0.f, 0.f};
        acc[rr][1] = (f32x4){0.f, 0.f, 0.f, 0.f};
    }

    const char* wbase = (const char*)wl;
    const int afix = (lm << 6) + (lg << 4);
    const char* xlb = reinterpret_cast<const char*>(xl);

    #pragma unroll
    for (int da = 0; da < 5; ++da) {
        #pragma unroll
        for (int db = 0; db < 5; ++db) {
            const int t = da * 5 + db;
            bf16x8 a0 = *reinterpret_cast<const bf16x8*>(wbase + (t << 11) + afix);
            bf16x8 a1 = *reinterpret_cast<const bf16x8*>(wbase + (t << 11) + 1024 + afix);
            const int col  = lm + db;
            const int coff = (col << 6) + ((lg ^ (col & 3)) << 4);
            #pragma unroll
            for (int rr = 0; rr < 4; ++rr) {
                const int row = rbase + rr + da;
                bf16x8 bf = *reinterpret_cast<const bf16x8*>(xlb + row * 1280 + coff);
                acc[rr][0] = __builtin_amdgcn_mfma_f32_16x16x32_bf16(a0, bf, acc[rr][0], 0, 0, 0);
                acc[rr][1] = __builtin_amdgcn_mfma_f32_16x16x32_bf16(a1, bf, acc[rr][1], 0, 0, 0);
            }
        }
    }

    const int j = j0 + lm;
    #pragma unroll
    for (int rr = 0; rr < 4; ++rr) {
        const int i = i0 + rbase + rr;
        if (i < HW_ && j < HW_) {
            size_t rowoff = (size_t)(b * NCH) * PLANE + (size_t)i * HW_ + j;
            #pragma unroll
            for (int mt = 0; mt < 2; ++mt)
                #pragma unroll
                for (int q = 0; q < 4; ++q) {
                    int o = mt * 16 + lg * 4 + q;
                    out[rowoff + (size_t)o * PLANE] = acc[rr][mt][q];
                }
        }
    }
}

extern "C" void kernel_launch(void* const* d_in, const int* in_sizes, int n_in,
                              void* d_out, int out_size, void* d_ws, size_t ws_size,
                              hipStream_t stream) {
    const float* x = (const float*)d_in[0];
    const float* w = (const float*)d_in[1];
    float* out = (float*)d_out;

    if (ws_size >= WS_NEED) {
        unsigned short* xpad = (unsigned short*)d_ws;
        unsigned short* wp   = (unsigned short*)((char*)d_ws + WP_OFF_BYTES);
        hipLaunchKernelGGL(pad_pack, dim3(8 * PADW + 100), dim3(256), 0, stream,
                           x, xpad, w, wp);
        hipLaunchKernelGGL(conv_mfma_v5, dim3(1152), dim3(256), 0, stream,
                           (const unsigned short*)xpad, (const unsigned short*)wp, out);
    } else {
        hipLaunchKernelGGL(conv_mfma_fb, dim3(2048), dim3(256), 0, stream, x, w, out);
    }
}